// Round 1
// baseline (152.924 us; speedup 1.0000x reference)
//
#include <hip/hip_runtime.h>
#include <math.h>

// SVD++ scoring, R7: position-parallel restructure.
// Old design rounded every segment (mean n~50) up to 64 gathered rows:
// E[ceil(n/64)]*64 = 88.6 rows fetched per 50 valid = 1.77x gather instrs,
// with masked slots burning L1/TA issue bandwidth, plus per-segment super
// serialization. New design: kernel 1 assigns one wave per 64 *global*
// positions of flat_implicit (zero waste, perfect balance). Each lane
// binary-searches its segment once; each 16-lane group owns 16 consecutive
// positions (~1.3 segments), accumulates float4 partial sums per segment
// run, and flushes one dot + 16-lane reduce + atomicAdd(out[seg]) per run.
// Kernel 2 adds u.i, /sqrt(n), and biases. `out` doubles as the segment
// accumulator (kernel 0 zeroes it) so d_ws is not needed.

#define K1_WAVES 4

__global__ void svdpp_zero(float* __restrict__ out, int B)
{
    const int i = blockIdx.x * blockDim.x + threadIdx.x;
    if (i < B) out[i] = 0.f;
}

#define LOADIDX(d) const int idx##d = __shfl(my_idx, (sub << 4) | (d), 64);
#define LOADVAL(d) const float4 v##d = impv[(size_t)idx##d * 16 + l16];

// flush current run: dot(acc, i4) reduced over the 16-lane group -> atomic
#define FLUSH()                                                              \
    {                                                                        \
        float p = acc.x * i4.x + acc.y * i4.y + acc.z * i4.z + acc.w * i4.w; \
        p += __shfl_xor(p, 1, 64);                                           \
        p += __shfl_xor(p, 2, 64);                                           \
        p += __shfl_xor(p, 4, 64);                                           \
        p += __shfl_xor(p, 8, 64);                                           \
        if (l16 == 0) atomicAdd(&out[cur], p);                               \
    }

// one position of this group's 16: if its segment differs from the open
// run, flush and start a new run (sd is uniform across the 16-lane group,
// so the branch and the FLUSH shuffles are group-coherent).
#define STEP(d)                                                              \
    {                                                                        \
        const int sd = __shfl(seg, (sub << 4) | (d), 64);                    \
        if (sd != cur) {                                                     \
            FLUSH();                                                         \
            cur = sd;                                                        \
            i4  = ((const float4*)(item_emb + (size_t)item_ids[cur] * 64))[l16]; \
            acc = make_float4(0.f, 0.f, 0.f, 0.f);                           \
        }                                                                    \
        if (base + (sub << 4) + (d) < N) {                                   \
            acc.x += v##d.x; acc.y += v##d.y;                                \
            acc.z += v##d.z; acc.w += v##d.w;                                \
        }                                                                    \
    }

__global__ __launch_bounds__(256, 1) void svdpp_gather(
    const int* __restrict__ item_ids,
    const int* __restrict__ offsets,
    const int* __restrict__ flat_implicit,
    const float* __restrict__ item_emb,
    const float* __restrict__ imp_emb,
    float* __restrict__ out,
    int B, int N)
{
    const int wave = threadIdx.x >> 6;
    const int lane = threadIdx.x & 63;
    const int base = (blockIdx.x * K1_WAVES + wave) << 6;
    if (base >= N) return;

    const int sub = lane >> 4;   // 0..3: group = 16 consecutive positions
    const int l16 = lane & 15;   // float4 slot within a 256B row

    const int a  = base + lane;            // this lane's global position
    const int ac = (a < N) ? a : (N - 1);  // clamped (N%64==0 in practice)

    // coalesced index load, issued first
    const int my_idx = flat_implicit[ac];

    // per-lane segment id: upper_bound(offsets, ac) - 1.
    // 14 dependent loads on a 64KB array that is hot in every L1/L2.
    int lo = 0, hi = B;
    while (lo < hi) {
        const int mid = (lo + hi) >> 1;
        if (offsets[mid] <= ac) lo = mid + 1; else hi = mid;
    }
    const int seg = lo - 1;   // offsets[0]==0 -> seg >= 0

    // prefetch the first run's item-embedding fragment for this group
    int cur = __shfl(seg, sub << 4, 64);
    float4 i4 = ((const float4*)(item_emb + (size_t)item_ids[cur] * 64))[l16];
    float4 acc = make_float4(0.f, 0.f, 0.f, 0.f);

    // distribute indices and issue all 16 row gathers back-to-back;
    // instr d fetches, for group `sub`, the row of position base+sub*16+d
    const float4* impv = (const float4*)imp_emb;
    LOADIDX(0)  LOADIDX(1)  LOADIDX(2)  LOADIDX(3)
    LOADIDX(4)  LOADIDX(5)  LOADIDX(6)  LOADIDX(7)
    LOADIDX(8)  LOADIDX(9)  LOADIDX(10) LOADIDX(11)
    LOADIDX(12) LOADIDX(13) LOADIDX(14) LOADIDX(15)

    LOADVAL(0)  LOADVAL(1)  LOADVAL(2)  LOADVAL(3)
    LOADVAL(4)  LOADVAL(5)  LOADVAL(6)  LOADVAL(7)
    LOADVAL(8)  LOADVAL(9)  LOADVAL(10) LOADVAL(11)
    LOADVAL(12) LOADVAL(13) LOADVAL(14) LOADVAL(15)

    // all 16 gathers in flight before any consumption
    __builtin_amdgcn_sched_barrier(0);

    STEP(0)  STEP(1)  STEP(2)  STEP(3)
    STEP(4)  STEP(5)  STEP(6)  STEP(7)
    STEP(8)  STEP(9)  STEP(10) STEP(11)
    STEP(12) STEP(13) STEP(14) STEP(15)

    FLUSH();
}

__global__ __launch_bounds__(256, 1) void svdpp_final(
    const int* __restrict__ user_ids,
    const int* __restrict__ item_ids,
    const int* __restrict__ offsets,
    const float* __restrict__ user_emb,
    const float* __restrict__ item_emb,
    const float* __restrict__ user_bias,
    const float* __restrict__ item_bias,
    const float* __restrict__ global_bias,
    float* __restrict__ out,
    int B, int N)
{
    const int l16 = threadIdx.x & 15;
    const int b   = blockIdx.x * 16 + (threadIdx.x >> 4);
    if (b >= B) return;

    const int user = user_ids[b];
    const int item = item_ids[b];

    const float4 u4 = ((const float4*)(user_emb + (size_t)user * 64))[l16];
    const float4 i4 = ((const float4*)(item_emb + (size_t)item * 64))[l16];

    float p = u4.x * i4.x + u4.y * i4.y + u4.z * i4.z + u4.w * i4.w;
    p += __shfl_xor(p, 1, 64);
    p += __shfl_xor(p, 2, 64);
    p += __shfl_xor(p, 4, 64);
    p += __shfl_xor(p, 8, 64);

    if (l16 == 0) {
        const int start = offsets[b];
        const int end   = (b + 1 < B) ? offsets[b + 1] : N;
        const int n     = end - start;
        const float norm = (n > 0) ? sqrtf((float)n) : 1.f;
        out[b] = p + out[b] / norm + user_bias[item == item ? user : user]
               + item_bias[item] + global_bias[0];
    }
}

extern "C" void kernel_launch(void* const* d_in, const int* in_sizes, int n_in,
                              void* d_out, int out_size, void* d_ws, size_t ws_size,
                              hipStream_t stream) {
    const int*   user_ids      = (const int*)  d_in[0];
    const int*   item_ids      = (const int*)  d_in[1];
    const int*   offsets       = (const int*)  d_in[2];
    const int*   flat_implicit = (const int*)  d_in[3];
    const float* user_emb      = (const float*)d_in[4];
    const float* item_emb      = (const float*)d_in[5];
    const float* imp_emb       = (const float*)d_in[6];
    const float* user_bias     = (const float*)d_in[7];
    const float* item_bias     = (const float*)d_in[8];
    const float* global_bias   = (const float*)d_in[9];
    float* out = (float*)d_out;

    const int B = in_sizes[0];
    const int N = in_sizes[3];

    svdpp_zero<<<(B + 255) / 256, 256, 0, stream>>>(out, B);

    const int waves = (N + 63) / 64;
    const int g1 = (waves + K1_WAVES - 1) / K1_WAVES;
    svdpp_gather<<<g1, K1_WAVES * 64, 0, stream>>>(
        item_ids, offsets, flat_implicit, item_emb, imp_emb, out, B, N);

    svdpp_final<<<(B + 15) / 16, 256, 0, stream>>>(
        user_ids, item_ids, offsets, user_emb, item_emb,
        user_bias, item_bias, global_bias, out, B, N);
}